// Round 9
// baseline (433.210 us; speedup 1.0000x reference)
//
#include <hip/hip_runtime.h>
#include <math.h>

// SNN forward, fused per batch element. Inputs f32, output f32 [2048][200].
// R9: 4 waves x 64 C-cols each (256 thr). Halves the two VALU duplications
// that bound R8: expand8 now feeds 4 MFMAs (4x dup instead of 8x), and the
// membrane scan uses all 64 lanes for 64 cols (ballot = full group mask).
// Barrier-free hidden layers (wave-local sc, bits ping-pong, 1 barrier/layer).
// 2 blocks/CU (LDS 69 KB, VGPR ~200 under launch_bounds(256,2)).

#define T_N 150
#define DIN 20
#define H 256
#define NOUT 200
#define NMT 10
#define CST 20           // sc col stride (f32): 16 rows + 4 pad, 16B-aligned
#define SCB 5120         // sc buffer stride (f32) = 256 cols * CST
#define XAP 40           // xa row stride (bf16)
#define BW 12            // bits row stride (dwords)

#define WS_W1 0
#define WS_W2 5120
#define WS_W3 70656
#define WS_W4 136192
#define WS_WO 201728
#define WS_TOT 252928

typedef short s16x8 __attribute__((ext_vector_type(8)));
typedef float f32x4 __attribute__((ext_vector_type(4)));
typedef unsigned int u32x4 __attribute__((ext_vector_type(4)));

__device__ __forceinline__ unsigned short f2bf(float f) {
  union { float f; unsigned int i; } v; v.f = f;
  unsigned int r = v.i + 0x7FFFu + ((v.i >> 16) & 1u);
  return (unsigned short)(r >> 16);
}

__global__ void cvt_weights(const float* __restrict__ W1, const float* __restrict__ W2,
                            const float* __restrict__ W3, const float* __restrict__ W4,
                            const float* __restrict__ Wo, unsigned short* __restrict__ ws) {
  int idx = blockIdx.x * blockDim.x + threadIdx.x;
  int stride = gridDim.x * blockDim.x;
  for (int i = idx; i < WS_TOT; i += stride) {
    float v;
    if (i < WS_W2)      v = W1[i - WS_W1];
    else if (i < WS_W3) v = W2[i - WS_W2];
    else if (i < WS_W4) v = W3[i - WS_W3];
    else if (i < WS_WO) v = W4[i - WS_W4];
    else                v = Wo[i - WS_WO];
    ws[i] = f2bf(v);
  }
}

// expand 8 spike bits (byte t) -> packed-bf16 x8 fragment (0.0 / 1.0)
__device__ __forceinline__ s16x8 expand8(unsigned int t) {
  unsigned int r2 = t * 0x8001u;   // bit 2j -> pos 2j ; bit 2j+1 -> pos 16+2j
  u32x4 d;
  d[0] = (r2 & 0x00010001u) * 0x3F80u;
  d[1] = (r2 & 0x00040004u) * 0x0FE0u;
  d[2] = (r2 & 0x00100010u) * 0x03F8u;
  d[3] = (r2 & 0x00400040u) * 0x00FEu;
  union { u32x4 u; s16x8 s; } cv; cv.u = d;
  return cv.s;
}

__global__ __launch_bounds__(256, 2) void snn_fused(
    const float* __restrict__ x,             // [2048][150][20] f32
    const unsigned short* __restrict__ wsb,  // bf16 weights (d_ws)
    const float* __restrict__ b1,            // [256] f32
    const float* __restrict__ b2,
    const float* __restrict__ b3,
    const float* __restrict__ b4,
    float* __restrict__ out)                 // [2048][200] f32
{
  __shared__ float sc[2 * SCB];              // 40960 B: col-major C scratch (dbuf)
  __shared__ unsigned int bits[2][160 * BW]; // 15360 B: spike bits, ping-pong
  __shared__ unsigned short xa[160 * XAP];   // 12800 B: padded bf16 x (layer 1)
                                             // total 69120 B -> 2 blocks/CU

  const int tid  = threadIdx.x;
  const int lane = tid & 63;
  const int wave = tid >> 6;    // 0..3
  const int c16  = lane & 15;   // MFMA: A row m / B col n / C col
  const int quad = lane >> 4;
  const int shq  = quad * 8;    // bit shift for this lane's mask byte
  const int bidx = blockIdx.x;
  const int colw = 64 * wave;   // wave owns cols [64w, 64w+64)
  const int cb   = colw + c16;  // col of tile 0; tiles i at cb + 16i

  // C-store: wave-local region of sc, col-major
  auto store_c = [&](int sb, f32x4* c) {
    #pragma unroll
    for (int i = 0; i < 4; ++i)
      *(f32x4*)&sc[sb * SCB + (cb + 16 * i) * CST + quad * 4] = c[i];
  };

  // membrane scan of tile mt: 64 lanes own the wave's 64 cols (wave-local,
  // no barrier). Full 64-bit ballot = this wave's 2 dwords of the row mask.
  auto scan_tile = [&](int mt, int sb, float& m, unsigned int* wbits) {
    const f32x4* vp = (const f32x4*)&sc[sb * SCB + (colw + lane) * CST];
    f32x4 v[4];
    #pragma unroll
    for (int j = 0; j < 4; ++j) v[j] = vp[j];
    unsigned long long keep = 0ull;
    #pragma unroll
    for (int r = 0; r < 16; ++r) {
      int t = mt * 16 + r;
      if (t < T_N) {  // block-uniform
        float inp = v[r >> 2][r & 3];            // bias folded into C-init
        float sel = (m > 1.0f) ? (inp - 1.0f) : inp;
        m = 0.9f * m + sel;
        unsigned long long msk = __ballot(m > 1.0f);
        if (lane == r) keep = msk;
      }
    }
    if (lane < 16)
      *(unsigned long long*)&wbits[(mt * 16 + lane) * BW + 2 * wave] = keep;
  };

  // ---- init: zero xa pads and bits pad rows; stage x as bf16 ----
  for (int i = tid; i < (160 * XAP) / 2; i += 256) ((unsigned int*)xa)[i] = 0;
  for (int i = tid; i < 2 * 160 * BW; i += 256) ((unsigned int*)bits)[i] = 0;
  __syncthreads();
  const float* xb = x + (size_t)bidx * (T_N * DIN);
  for (int e = tid; e < T_N * DIN; e += 256) {
    int t = e / DIN;
    int i = e - t * DIN;
    xa[t * XAP + i] = f2bf(xb[e]);
  }

  // ---- layer 1: x @ W1^T (K=20 pad 32) -> bits[0]; barrier-free ----
  {
    s16x8 w1f[4];
    #pragma unroll
    for (int i = 0; i < 4; ++i) {
      int n = cb + 16 * i;
      #pragma unroll
      for (int j = 0; j < 8; ++j) {
        int k = shq + j;
        w1f[i][j] = (k < DIN) ? (short)wsb[WS_W1 + n * DIN + k] : (short)0;
      }
      asm volatile("" : "+v"(w1f[i]));
    }
    float bc[4];
    #pragma unroll
    for (int i = 0; i < 4; ++i) bc[i] = b1[cb + 16 * i];
    float m = 0.0f;
    __syncthreads();  // xa staged
    for (int mt = 0; mt < NMT; ++mt) {
      const s16x8 a1 = *(const s16x8*)&xa[(mt * 16 + c16) * XAP + shq];
      f32x4 c[4];
      #pragma unroll
      for (int i = 0; i < 4; ++i) { f32x4 z = {bc[i], bc[i], bc[i], bc[i]}; c[i] = z; }
      #pragma unroll
      for (int i = 0; i < 4; ++i)
        c[i] = __builtin_amdgcn_mfma_f32_16x16x32_bf16(a1, w1f[i], c[i], 0, 0, 0);
      if (mt > 0) scan_tile(mt - 1, (mt - 1) & 1, m, bits[0]);
      store_c(mt & 1, c);
    }
    scan_tile(9, 1, m, bits[0]);
  }
  __syncthreads();  // phase barrier: bits[0] complete

  // ---- layers 2..4: barrier-free tile loop; bits ping-pong ----
  const float* bsl[3] = {b2, b3, b4};
  const int wofs[3] = {WS_W2, WS_W3, WS_W4};
  for (int l = 0; l < 3; ++l) {
    const unsigned short* wl = wsb + wofs[l];
    const unsigned int* rbits = bits[l & 1];
    unsigned int* wbits = bits[(l & 1) ^ 1];
    s16x8 wf[4][8];
    #pragma unroll
    for (int i = 0; i < 4; ++i) {
      int n = cb + 16 * i;
      #pragma unroll
      for (int ks = 0; ks < 8; ++ks) {
        wf[i][ks] = *(const s16x8*)(wl + n * H + ks * 32 + shq);
        asm volatile("" : "+v"(wf[i][ks]));
      }
    }
    float bc[4];
    #pragma unroll
    for (int i = 0; i < 4; ++i) bc[i] = bsl[l][cb + 16 * i];
    float m = 0.0f;
    for (int mt = 0; mt < NMT; ++mt) {
      const unsigned int* bp = &rbits[(mt * 16 + c16) * BW];
      u32x4 rm0 = *(const u32x4*)bp;
      u32x4 rm1 = *(const u32x4*)(bp + 4);
      unsigned int rm[8] = {rm0[0], rm0[1], rm0[2], rm0[3],
                            rm1[0], rm1[1], rm1[2], rm1[3]};
      f32x4 c[4];
      #pragma unroll
      for (int i = 0; i < 4; ++i) { f32x4 z = {bc[i], bc[i], bc[i], bc[i]}; c[i] = z; }
      #pragma unroll
      for (int ks = 0; ks < 8; ++ks) {
        s16x8 a = expand8((rm[ks] >> shq) & 0xFFu);
        #pragma unroll
        for (int i = 0; i < 4; ++i)
          c[i] = __builtin_amdgcn_mfma_f32_16x16x32_bf16(a, wf[i][ks], c[i], 0, 0, 0);
      }
      if (mt > 0) scan_tile(mt - 1, (mt - 1) & 1, m, wbits);
      store_c(mt & 1, c);
    }
    scan_tile(9, 1, m, wbits);
    __syncthreads();  // phase barrier: wbits complete
  }

  // ---- output layer (reads bits[1]): GEMM + mo-scan + softmax (t > 50) ----
  {
    s16x8 wo[4][8];
    #pragma unroll
    for (int i = 0; i < 4; ++i) {
      int n = cb + 16 * i;
      bool valid = (n < NOUT);
      #pragma unroll
      for (int ks = 0; ks < 8; ++ks) {
        s16x8 z = {0, 0, 0, 0, 0, 0, 0, 0};
        wo[i][ks] = valid ? *(const s16x8*)(wsb + WS_WO + n * H + ks * 32 + shq) : z;
        asm volatile("" : "+v"(wo[i][ks]));
      }
    }

    float mo = 0.0f;
    float a0 = 0.f, a1 = 0.f, a2 = 0.f, a3 = 0.f;

    auto moscan = [&](int mt, int sb) {
      if (tid < 208) {
        f32x4* vp = (f32x4*)&sc[sb * SCB + tid * CST];
        f32x4 v[4];
        #pragma unroll
        for (int j = 0; j < 4; ++j) v[j] = vp[j];
        #pragma unroll
        for (int r = 0; r < 16; ++r) {
          int t = mt * 16 + r;
          if (t < T_N) {
            float reset = (mo > 1.0f) ? 1.0f : 0.0f;
            mo = 0.9f * mo + v[r / 4][r % 4] - reset;
            v[r / 4][r % 4] = mo;
          }
        }
        #pragma unroll
        for (int j = 0; j < 4; ++j) vp[j] = v[j];
      }
    };
    auto softmax_t = [&](int mt, int sb) {
      #pragma unroll
      for (int rr = 0; rr < 4; ++rr) {
        int r = 4 * wave + rr;
        int t = mt * 16 + r;
        if (t > 50 && t < T_N) {        // wave-uniform
          const float* sb_p = &sc[sb * SCB + r];
          float v0 = sb_p[lane * CST];
          float v1 = sb_p[(64 + lane) * CST];
          float v2 = sb_p[(128 + lane) * CST];
          bool has3 = (lane < 8);        // n=192+lane valid only for n<200
          float v3 = has3 ? sb_p[(192 + lane) * CST] : -INFINITY;
          float mx = fmaxf(fmaxf(v0, v1), fmaxf(v2, v3));
          #pragma unroll
          for (int d = 32; d >= 1; d >>= 1) mx = fmaxf(mx, __shfl_xor(mx, d));
          float e0 = __expf(v0 - mx), e1 = __expf(v1 - mx), e2 = __expf(v2 - mx);
          float e3 = has3 ? __expf(v3 - mx) : 0.0f;
          float s = e0 + e1 + e2 + e3;
          #pragma unroll
          for (int d = 32; d >= 1; d >>= 1) s += __shfl_xor(s, d);
          float inv = 1.0f / s;
          a0 += e0 * inv; a1 += e1 * inv; a2 += e2 * inv; a3 += e3 * inv;
        }
      }
    };

    for (int mt = 0; mt < NMT; ++mt) {
      const unsigned int* bp = &bits[1][(mt * 16 + c16) * BW];
      u32x4 rm0 = *(const u32x4*)bp;
      u32x4 rm1 = *(const u32x4*)(bp + 4);
      unsigned int rm[8] = {rm0[0], rm0[1], rm0[2], rm0[3],
                            rm1[0], rm1[1], rm1[2], rm1[3]};
      f32x4 c[4];
      #pragma unroll
      for (int i = 0; i < 4; ++i) { f32x4 z = {0.f, 0.f, 0.f, 0.f}; c[i] = z; }
      #pragma unroll
      for (int ks = 0; ks < 8; ++ks) {
        s16x8 a = expand8((rm[ks] >> shq) & 0xFFu);
        #pragma unroll
        for (int i = 0; i < 4; ++i)
          c[i] = __builtin_amdgcn_mfma_f32_16x16x32_bf16(a, wo[i][ks], c[i], 0, 0, 0);
      }
      if (mt > 0) moscan(mt - 1, (mt - 1) & 1);
      store_c(mt & 1, c);
      __syncthreads();
      if (mt > 0) { softmax_t(mt - 1, (mt - 1) & 1); __syncthreads(); }
    }
    moscan(9, 1);  __syncthreads();
    softmax_t(9, 1); __syncthreads();

    // merge 4 per-wave accumulators (sc reused flat), store f32
    sc[wave * 260 + lane]       = a0;
    sc[wave * 260 + 64 + lane]  = a1;
    sc[wave * 260 + 128 + lane] = a2;
    if (lane < 8) sc[wave * 260 + 192 + lane] = a3;
    __syncthreads();
    if (tid < NOUT) {
      float v = 0.f;
      #pragma unroll
      for (int w = 0; w < 4; ++w) v += sc[w * 260 + tid];
      out[(size_t)bidx * NOUT + tid] = v;
    }
  }
}

extern "C" void kernel_launch(void* const* d_in, const int* in_sizes, int n_in,
                              void* d_out, int out_size, void* d_ws, size_t ws_size,
                              hipStream_t stream) {
  (void)in_sizes; (void)n_in; (void)ws_size; (void)out_size;
  unsigned short* wsb = (unsigned short*)d_ws;
  cvt_weights<<<256, 256, 0, stream>>>(
      (const float*)d_in[1], (const float*)d_in[3], (const float*)d_in[5],
      (const float*)d_in[7], (const float*)d_in[9], wsb);
  snn_fused<<<2048, 256, 0, stream>>>(
      (const float*)d_in[0], wsb,
      (const float*)d_in[2], (const float*)d_in[4],
      (const float*)d_in[6], (const float*)d_in[8],
      (float*)d_out);
}

// Round 10
// 390.213 us; speedup vs baseline: 1.1102x; 1.1102x over previous
//
#include <hip/hip_runtime.h>
#include <math.h>

// SNN forward, fused. Inputs f32, output f32 [2048][200].
// R10: TWO batch elements per block sharing the per-wave weight registers
// (weights are the reg hog: 128/wave for 64 cols; per-elem state ~100 more ->
// ~240 total, 2 waves/SIMD -> 4 elems in flight/CU vs R9's 2). Latency hiding
// via intra-wave ILP: two independent MFMA chains + two independent scans.
// Single-buffered sc per elem (same-wave in-order LDS read->write), bits
// ping-pong per elem, xa aliased onto elem's 2nd bits buffer. 72 KB LDS ->
// 2 blocks/CU. grid=1024 x 256 thr.

#define T_N 150
#define DIN 20
#define H 256
#define NOUT 200
#define NMT 10
#define CST 20             // sc col stride (f32): 16 rows + 4 pad
#define SCB 5120           // per-elem sc buffer (f32) = 256 cols * CST
#define XAP 24             // xa row stride (bf16): 20 data + 4 zero pad
#define BW 12              // bits row stride (dwords)
#define BITN (160 * BW + 8)  // per bits buffer (+8 dword tail pad for b128 A-reads)

#define WS_W1 0
#define WS_W2 5120
#define WS_W3 70656
#define WS_W4 136192
#define WS_WO 201728
#define WS_TOT 252928

typedef short s16x8 __attribute__((ext_vector_type(8)));
typedef float f32x4 __attribute__((ext_vector_type(4)));
typedef unsigned int u32x4 __attribute__((ext_vector_type(4)));

__device__ __forceinline__ unsigned short f2bf(float f) {
  union { float f; unsigned int i; } v; v.f = f;
  unsigned int r = v.i + 0x7FFFu + ((v.i >> 16) & 1u);
  return (unsigned short)(r >> 16);
}

__global__ void cvt_weights(const float* __restrict__ W1, const float* __restrict__ W2,
                            const float* __restrict__ W3, const float* __restrict__ W4,
                            const float* __restrict__ Wo, unsigned short* __restrict__ ws) {
  int idx = blockIdx.x * blockDim.x + threadIdx.x;
  int stride = gridDim.x * blockDim.x;
  for (int i = idx; i < WS_TOT; i += stride) {
    float v;
    if (i < WS_W2)      v = W1[i - WS_W1];
    else if (i < WS_W3) v = W2[i - WS_W2];
    else if (i < WS_W4) v = W3[i - WS_W3];
    else if (i < WS_WO) v = W4[i - WS_W4];
    else                v = Wo[i - WS_WO];
    ws[i] = f2bf(v);
  }
}

// expand 8 spike bits (byte t) -> packed-bf16 x8 fragment (0.0 / 1.0)
__device__ __forceinline__ s16x8 expand8(unsigned int t) {
  unsigned int r2 = t * 0x8001u;   // bit 2j -> pos 2j ; bit 2j+1 -> pos 16+2j
  u32x4 d;
  d[0] = (r2 & 0x00010001u) * 0x3F80u;
  d[1] = (r2 & 0x00040004u) * 0x0FE0u;
  d[2] = (r2 & 0x00100010u) * 0x03F8u;
  d[3] = (r2 & 0x00400040u) * 0x00FEu;
  union { u32x4 u; s16x8 s; } cv; cv.u = d;
  return cv.s;
}

__global__ __launch_bounds__(256, 2) void snn_fused(
    const float* __restrict__ x,             // [2048][150][20] f32
    const unsigned short* __restrict__ wsb,  // bf16 weights (d_ws)
    const float* __restrict__ b1,            // [256] f32
    const float* __restrict__ b2,
    const float* __restrict__ b3,
    const float* __restrict__ b4,
    float* __restrict__ out)                 // [2048][200] f32
{
  __shared__ float sc[2 * SCB];                // 40960 B: per-elem C scratch (single-buf)
  __shared__ unsigned int ubits[2][2][BITN];   // 30976 B: per-elem spike bits, ping-pong
                                               // total 71936 B -> 2 blocks/CU

  const int tid  = threadIdx.x;
  const int lane = tid & 63;
  const int wave = tid >> 6;    // 0..3
  const int c16  = lane & 15;
  const int quad = lane >> 4;
  const int shq  = quad * 8;
  const int bidx = blockIdx.x;
  const int colw = 64 * wave;   // wave owns cols [64w, 64w+64)
  const int cb   = colw + c16;

  float* sc0 = sc;
  float* sc1 = sc + SCB;
  unsigned short* xa0 = (unsigned short*)&ubits[0][1][0];  // aliases elem0 bits buf 1
  unsigned short* xa1 = (unsigned short*)&ubits[1][1][0];  // aliases elem1 bits buf 1

  auto store_c = [&](float* scE, f32x4* c) {
    #pragma unroll
    for (int i = 0; i < 4; ++i)
      *(f32x4*)&scE[(cb + 16 * i) * CST + quad * 4] = c[i];
  };

  // membrane scan of tile mt: 64 lanes own the wave's 64 cols (wave-local).
  auto scan_tile = [&](int mt, const float* scE, float& m, unsigned int* wb) {
    const f32x4* vp = (const f32x4*)&scE[(colw + lane) * CST];
    f32x4 v[4];
    #pragma unroll
    for (int j = 0; j < 4; ++j) v[j] = vp[j];
    unsigned long long keep = 0ull;
    #pragma unroll
    for (int r = 0; r < 16; ++r) {
      int t = mt * 16 + r;
      if (t < T_N) {  // block-uniform
        float inp = v[r >> 2][r & 3];
        float sel = (m > 1.0f) ? (inp - 1.0f) : inp;
        m = 0.9f * m + sel;
        unsigned long long msk = __ballot(m > 1.0f);
        if (lane == r) keep = msk;
      }
    }
    if (lane < 16)
      *(unsigned long long*)&wb[(mt * 16 + lane) * BW + 2 * wave] = keep;
  };

  auto load_masks = [&](const unsigned int* rb, int mt, unsigned int* rm) {
    const unsigned int* bp = &rb[(mt * 16 + c16) * BW];
    u32x4 a = *(const u32x4*)bp;
    u32x4 b = *(const u32x4*)(bp + 4);
    rm[0] = a[0]; rm[1] = a[1]; rm[2] = a[2]; rm[3] = a[3];
    rm[4] = b[0]; rm[5] = b[1]; rm[6] = b[2]; rm[7] = b[3];
  };

  // ---- init: zero the xa regions (k-pad + tail rows must be 0), stage x ----
  for (int i = tid; i < BITN; i += 256) { ubits[0][1][i] = 0; ubits[1][1][i] = 0; }
  __syncthreads();
  {
    const float* xb0 = x + (size_t)(2 * bidx) * (T_N * DIN);
    const float* xb1 = xb0 + (T_N * DIN);
    for (int i = tid; i < T_N * XAP; i += 256) {
      int t = i / XAP, j = i - t * XAP;
      unsigned short v0 = 0, v1 = 0;
      if (j < DIN) { v0 = f2bf(xb0[t * DIN + j]); v1 = f2bf(xb1[t * DIN + j]); }
      xa0[i] = v0; xa1[i] = v1;
    }
  }

  // ---- layer 1: x @ W1^T (K=20 pad 32) -> ubits[e][0]; barrier-free ----
  {
    s16x8 w1f[4];
    #pragma unroll
    for (int i = 0; i < 4; ++i) {
      int n = cb + 16 * i;
      #pragma unroll
      for (int j = 0; j < 8; ++j) {
        int k = shq + j;
        w1f[i][j] = (k < DIN) ? (short)wsb[WS_W1 + n * DIN + k] : (short)0;
      }
      asm volatile("" : "+v"(w1f[i]));
    }
    float bc[4];
    #pragma unroll
    for (int i = 0; i < 4; ++i) bc[i] = b1[cb + 16 * i];
    float m0 = 0.0f, m1 = 0.0f;
    __syncthreads();  // xa staged
    for (int mt = 0; mt < NMT; ++mt) {
      const s16x8 a0 = *(const s16x8*)&xa0[(mt * 16 + c16) * XAP + shq];
      const s16x8 a1 = *(const s16x8*)&xa1[(mt * 16 + c16) * XAP + shq];
      f32x4 c0[4], c1[4];
      #pragma unroll
      for (int i = 0; i < 4; ++i) {
        f32x4 z = {bc[i], bc[i], bc[i], bc[i]};
        c0[i] = z; c1[i] = z;
      }
      #pragma unroll
      for (int i = 0; i < 4; ++i) {
        c0[i] = __builtin_amdgcn_mfma_f32_16x16x32_bf16(a0, w1f[i], c0[i], 0, 0, 0);
        c1[i] = __builtin_amdgcn_mfma_f32_16x16x32_bf16(a1, w1f[i], c1[i], 0, 0, 0);
      }
      if (mt > 0) scan_tile(mt - 1, sc0, m0, ubits[0][0]);
      store_c(sc0, c0);
      if (mt > 0) scan_tile(mt - 1, sc1, m1, ubits[1][0]);
      store_c(sc1, c1);
    }
    scan_tile(9, sc0, m0, ubits[0][0]);
    scan_tile(9, sc1, m1, ubits[1][0]);
  }
  __syncthreads();  // bits buf 0 complete (both elems)

  // ---- layers 2..4: barrier-free, bits ping-pong per elem ----
  const float* bsl[3] = {b2, b3, b4};
  const int wofs[3] = {WS_W2, WS_W3, WS_W4};
  for (int l = 0; l < 3; ++l) {
    const unsigned short* wl = wsb + wofs[l];
    const int rp = l & 1, wp = rp ^ 1;
    s16x8 wf[4][8];
    #pragma unroll
    for (int i = 0; i < 4; ++i) {
      int n = cb + 16 * i;
      #pragma unroll
      for (int ks = 0; ks < 8; ++ks) {
        wf[i][ks] = *(const s16x8*)(wl + n * H + ks * 32 + shq);
        asm volatile("" : "+v"(wf[i][ks]));
      }
    }
    float bc[4];
    #pragma unroll
    for (int i = 0; i < 4; ++i) bc[i] = bsl[l][cb + 16 * i];
    float m0 = 0.0f, m1 = 0.0f;
    for (int mt = 0; mt < NMT; ++mt) {
      unsigned int rm0[8], rm1[8];
      load_masks(ubits[0][rp], mt, rm0);
      load_masks(ubits[1][rp], mt, rm1);
      f32x4 c0[4], c1[4];
      #pragma unroll
      for (int i = 0; i < 4; ++i) {
        f32x4 z = {bc[i], bc[i], bc[i], bc[i]};
        c0[i] = z; c1[i] = z;
      }
      #pragma unroll
      for (int ks = 0; ks < 8; ++ks) {
        s16x8 a0 = expand8((rm0[ks] >> shq) & 0xFFu);
        #pragma unroll
        for (int i = 0; i < 4; ++i)
          c0[i] = __builtin_amdgcn_mfma_f32_16x16x32_bf16(a0, wf[i][ks], c0[i], 0, 0, 0);
      }
      #pragma unroll
      for (int ks = 0; ks < 8; ++ks) {
        s16x8 a1 = expand8((rm1[ks] >> shq) & 0xFFu);
        #pragma unroll
        for (int i = 0; i < 4; ++i)
          c1[i] = __builtin_amdgcn_mfma_f32_16x16x32_bf16(a1, wf[i][ks], c1[i], 0, 0, 0);
      }
      if (mt > 0) scan_tile(mt - 1, sc0, m0, ubits[0][wp]);
      store_c(sc0, c0);
      if (mt > 0) scan_tile(mt - 1, sc1, m1, ubits[1][wp]);
      store_c(sc1, c1);
    }
    scan_tile(9, sc0, m0, ubits[0][wp]);
    scan_tile(9, sc1, m1, ubits[1][wp]);
    __syncthreads();  // bits buf wp complete (both elems)
  }

  // ---- output layer (reads ubits[e][1]): GEMM + mo-scan + softmax (t>50) ----
  {
    s16x8 wo[4][8];
    #pragma unroll
    for (int i = 0; i < 4; ++i) {
      int n = cb + 16 * i;
      bool valid = (n < NOUT);
      #pragma unroll
      for (int ks = 0; ks < 8; ++ks) {
        s16x8 z = {0, 0, 0, 0, 0, 0, 0, 0};
        wo[i][ks] = valid ? *(const s16x8*)(wsb + WS_WO + n * H + ks * 32 + shq) : z;
        asm volatile("" : "+v"(wo[i][ks]));
      }
    }

    float mo0 = 0.0f, mo1 = 0.0f;
    float a00 = 0.f, a01 = 0.f, a02 = 0.f, a03 = 0.f;
    float a10 = 0.f, a11 = 0.f, a12 = 0.f, a13 = 0.f;

    auto moscan = [&](int mt, float* scE, float& mo) {
      if (tid < 208) {
        f32x4* vp = (f32x4*)&scE[tid * CST];
        f32x4 v[4];
        #pragma unroll
        for (int j = 0; j < 4; ++j) v[j] = vp[j];
        #pragma unroll
        for (int r = 0; r < 16; ++r) {
          int t = mt * 16 + r;
          if (t < T_N) {
            float reset = (mo > 1.0f) ? 1.0f : 0.0f;
            mo = 0.9f * mo + v[r >> 2][r & 3] - reset;
            v[r >> 2][r & 3] = mo;
          }
        }
        #pragma unroll
        for (int j = 0; j < 4; ++j) vp[j] = v[j];
      }
    };
    auto softmax_t = [&](int mt, const float* scE, float& s0, float& s1,
                         float& s2, float& s3) {
      #pragma unroll
      for (int rr = 0; rr < 4; ++rr) {
        int r = 4 * wave + rr;
        int t = mt * 16 + r;
        if (t > 50 && t < T_N) {        // wave-uniform
          const float* p = &scE[r];
          float v0 = p[lane * CST];
          float v1 = p[(64 + lane) * CST];
          float v2 = p[(128 + lane) * CST];
          bool has3 = (lane < 8);
          float v3 = has3 ? p[(192 + lane) * CST] : -INFINITY;
          float mx = fmaxf(fmaxf(v0, v1), fmaxf(v2, v3));
          #pragma unroll
          for (int d = 32; d >= 1; d >>= 1) mx = fmaxf(mx, __shfl_xor(mx, d));
          float e0 = __expf(v0 - mx), e1 = __expf(v1 - mx), e2 = __expf(v2 - mx);
          float e3 = has3 ? __expf(v3 - mx) : 0.0f;
          float s = e0 + e1 + e2 + e3;
          #pragma unroll
          for (int d = 32; d >= 1; d >>= 1) s += __shfl_xor(s, d);
          float inv = 1.0f / s;
          s0 += e0 * inv; s1 += e1 * inv; s2 += e2 * inv; s3 += e3 * inv;
        }
      }
    };

    for (int mt = 0; mt < NMT; ++mt) {
      unsigned int rm0[8], rm1[8];
      load_masks(ubits[0][1], mt, rm0);
      load_masks(ubits[1][1], mt, rm1);
      f32x4 c0[4], c1[4];
      #pragma unroll
      for (int i = 0; i < 4; ++i) { f32x4 z = {0.f, 0.f, 0.f, 0.f}; c0[i] = z; c1[i] = z; }
      #pragma unroll
      for (int ks = 0; ks < 8; ++ks) {
        s16x8 a0 = expand8((rm0[ks] >> shq) & 0xFFu);
        s16x8 a1 = expand8((rm1[ks] >> shq) & 0xFFu);
        #pragma unroll
        for (int i = 0; i < 4; ++i) {
          c0[i] = __builtin_amdgcn_mfma_f32_16x16x32_bf16(a0, wo[i][ks], c0[i], 0, 0, 0);
          c1[i] = __builtin_amdgcn_mfma_f32_16x16x32_bf16(a1, wo[i][ks], c1[i], 0, 0, 0);
        }
      }
      __syncthreads();              // prior softmax done reading sc
      store_c(sc0, c0);
      store_c(sc1, c1);
      __syncthreads();              // C complete (cross-wave)
      moscan(mt, sc0, mo0);
      moscan(mt, sc1, mo1);
      __syncthreads();              // membranes written (cross-wave)
      softmax_t(mt, sc0, a00, a01, a02, a03);
      softmax_t(mt, sc1, a10, a11, a12, a13);
    }
    __syncthreads();

    // merge 4 per-wave accumulators per elem via sc, store f32
    sc0[wave * 260 + lane]       = a00;
    sc0[wave * 260 + 64 + lane]  = a01;
    sc0[wave * 260 + 128 + lane] = a02;
    if (lane < 8) sc0[wave * 260 + 192 + lane] = a03;
    sc1[wave * 260 + lane]       = a10;
    sc1[wave * 260 + 64 + lane]  = a11;
    sc1[wave * 260 + 128 + lane] = a12;
    if (lane < 8) sc1[wave * 260 + 192 + lane] = a13;
    __syncthreads();
    if (tid < NOUT) {
      float v0 = 0.f, v1 = 0.f;
      #pragma unroll
      for (int w = 0; w < 4; ++w) {
        v0 += sc0[w * 260 + tid];
        v1 += sc1[w * 260 + tid];
      }
      out[(size_t)(2 * bidx) * NOUT + tid]     = v0;
      out[(size_t)(2 * bidx + 1) * NOUT + tid] = v1;
    }
  }
}

extern "C" void kernel_launch(void* const* d_in, const int* in_sizes, int n_in,
                              void* d_out, int out_size, void* d_ws, size_t ws_size,
                              hipStream_t stream) {
  (void)in_sizes; (void)n_in; (void)ws_size; (void)out_size;
  unsigned short* wsb = (unsigned short*)d_ws;
  cvt_weights<<<256, 256, 0, stream>>>(
      (const float*)d_in[1], (const float*)d_in[3], (const float*)d_in[5],
      (const float*)d_in[7], (const float*)d_in[9], wsb);
  snn_fused<<<1024, 256, 0, stream>>>(
      (const float*)d_in[0], wsb,
      (const float*)d_in[2], (const float*)d_in[4],
      (const float*)d_in[6], (const float*)d_in[8],
      (float*)d_out);
}